// Round 16
// baseline (440.831 us; speedup 1.0000x reference)
//
#include <hip/hip_runtime.h>

typedef __attribute__((ext_vector_type(8))) short bf16x8;
typedef __attribute__((ext_vector_type(8))) unsigned short ushort8;
typedef __attribute__((ext_vector_type(4))) float f32x4;
typedef __attribute__((ext_vector_type(2))) float f32x2;
typedef __attribute__((ext_vector_type(4))) unsigned int u32x4;
typedef __attribute__((ext_vector_type(2))) unsigned int u32x2;

__device__ __forceinline__ float bf2f(unsigned short u) {
  union { unsigned int i; float f; } v; v.i = ((unsigned int)u) << 16; return v.f;
}
__device__ __forceinline__ float asf(unsigned int u) {
  union { unsigned int i; float f; } v; v.i = u; return v.f;
}
__device__ __forceinline__ unsigned short f2bf(float f) {
  union { float f; unsigned int i; } v; v.f = f;
  unsigned int u = v.i;
  return (unsigned short)((u + 0x7FFFu + ((u >> 16) & 1u)) >> 16);
}
__device__ __forceinline__ void gload16(const void* g, void* l) {
  __builtin_amdgcn_global_load_lds(
      (const __attribute__((address_space(1))) void*)g,
      (__attribute__((address_space(3))) void*)l, 16, 0, 0);
}

// ---------- K-1: fp32 -> bf16 convert (w_qkv) ----------
__global__ __launch_bounds__(256) void cvt_f32_bf16(const float* __restrict__ s,
                                                    unsigned short* __restrict__ d, int n) {
  int i = blockIdx.x * 256 + threadIdx.x;
  if (i < n) d[i] = f2bf(s[i]);
}

// ---------- K0: x (B,C,N) fp32 -> Xt (B,N,C) bf16, LDS tiled, packed u32 stores ----------
__global__ __launch_bounds__(256) void transpose_x(const float* __restrict__ x,
                                                   unsigned short* __restrict__ xt) {
  __shared__ float tile[64][65];
  const int b = blockIdx.z, ct = blockIdx.y, nt = blockIdx.x;
  const int t = threadIdx.x;
  const int r0 = t >> 6, col = t & 63;
  const float* src = x + ((size_t)b * 512 + ct * 64) * 4096 + nt * 64;
#pragma unroll
  for (int i = 0; i < 16; ++i) {
    int r = i * 4 + r0;
    tile[r][col] = src[(size_t)r * 4096 + col];
  }
  __syncthreads();
  unsigned short* dst = xt + ((size_t)b * 4096 + nt * 64) * 512 + ct * 64;
  const int c2 = (t & 31) * 2;
  const int nsub = t >> 5;   // 0..7
#pragma unroll
  for (int i = 0; i < 8; ++i) {
    int n = i * 8 + nsub;
    unsigned int p;
    asm("v_cvt_pk_bf16_f32 %0, %1, %2" : "=v"(p) : "v"(tile[c2][n]), "v"(tile[c2 + 1][n]));
    *(unsigned int*)(dst + (size_t)n * 512 + c2) = p;
  }
}

// ---------- K1: QKV GEMM, persistent-N: one block per 256-row M-tile runs all 6 N-tiles ----------
// Continuous 48-tile pipeline (T = bx*8 + kt). Per-tile schedule identical to the verified
// m201-ordered 4-phase loop; C-write for each bx issued mid-loop (stores drain in shadow).
__global__ __launch_bounds__(512, 1) void gemm_qkv_pers(const unsigned short* __restrict__ A,
                                                        const unsigned short* __restrict__ B,
                                                        unsigned short* __restrict__ C) {
  __shared__ unsigned short lA[2][256 * 64];
  __shared__ unsigned short lB[2][256 * 64];
  const int bid = blockIdx.x;                   // 256 blocks
  const int by = (bid & 7) * 32 + (bid >> 3);   // XCD-chunked
  const size_t m0 = (size_t)by * 256;

  const int t = threadIdx.x;
  const int lane = t & 63;
  const int wid = t >> 6;
  const int wm = wid >> 2, wn = wid & 3;  // 2 x 4 waves, each owns 128x64 of C
  const int ro = lane & 15, kq = lane >> 4;

  const int srow = t >> 3;                // 0..63
  const int sslot = t & 7;
  const int kslot = sslot ^ (srow & 7);

  auto stageA = [&](int Tt, int h, int bbuf) {
    const int kt = Tt & 7;
    char* d = (char*)(&lA[bbuf][0]) + ((h * 128 + srow) * 64 + sslot * 8) * 2;
    const unsigned short* g = A + (m0 + h * 128 + srow) * 512 + kt * 64 + kslot * 8;
    gload16(g, d);
    gload16(g + (size_t)64 * 512, d + 64 * 128);
  };
  auto stageB = [&](int Tt, int h, int bbuf) {
    const int kt = Tt & 7;
    const size_t nb = (size_t)(Tt >> 3) * 256;
    char* d = (char*)(&lB[bbuf][0]) + ((h * 128 + srow) * 64 + sslot * 8) * 2;
    const unsigned short* g = B + (nb + h * 128 + srow) * 512 + kt * 64 + kslot * 8;
    gload16(g, d);
    gload16(g + (size_t)64 * 512, d + 64 * 128);
  };

  f32x4 acc[8][4] = {};

  // prologue: A(0), B(0) -> buf0; A(1) -> buf1   (12 loads in flight)
  stageA(0, 0, 0); stageA(0, 1, 0);
  stageB(0, 0, 0); stageB(0, 1, 0);
  stageA(1, 0, 1); stageA(1, 1, 1);
  asm volatile("s_waitcnt vmcnt(4)" ::: "memory");   // A(0)+B(0) landed
  __builtin_amdgcn_s_barrier();

#pragma unroll 1
  for (int T = 0; T < 48; ++T) {
    const int c = T & 1;
    const unsigned short* pa = &lA[c][0];
    const unsigned short* pb = &lB[c][0];
    const int slot0 = kq ^ (ro & 7);        // kk=0
    const int slot1 = (4 + kq) ^ (ro & 7);  // kk=1

    // ---- P0: reads q0 ; stage B(T+1)h0 ; barrier ; lgkm0 ; MFMA q0
    bf16x8 a0[8], a1[8], b0, b1, b2, b3;
#pragma unroll
    for (int i = 0; i < 8; ++i)
      a0[i] = *(const bf16x8*)&pa[(wm * 128 + i * 16 + ro) * 64 + slot0 * 8];
    b0 = *(const bf16x8*)&pb[(wn * 64 + 0 * 16 + ro) * 64 + slot0 * 8];
    b1 = *(const bf16x8*)&pb[(wn * 64 + 1 * 16 + ro) * 64 + slot0 * 8];
    if (T + 1 < 48) stageB(T + 1, 0, c ^ 1);
    asm volatile("" ::: "memory");
    __builtin_amdgcn_s_barrier();
    asm volatile("s_waitcnt lgkmcnt(0)" ::: "memory");
    __builtin_amdgcn_s_setprio(1);
#pragma unroll
    for (int i = 0; i < 8; ++i) {
      acc[i][0] = __builtin_amdgcn_mfma_f32_16x16x32_bf16(a0[i], b0, acc[i][0], 0, 0, 0);
      acc[i][1] = __builtin_amdgcn_mfma_f32_16x16x32_bf16(a0[i], b1, acc[i][1], 0, 0, 0);
    }
    __builtin_amdgcn_s_setprio(0);

    // ---- P1: reads q1 ; stage B(T+1)h1 ; barrier ; lgkm0 ; MFMA q1
    b2 = *(const bf16x8*)&pb[(wn * 64 + 2 * 16 + ro) * 64 + slot0 * 8];
    b3 = *(const bf16x8*)&pb[(wn * 64 + 3 * 16 + ro) * 64 + slot0 * 8];
    if (T + 1 < 48) stageB(T + 1, 1, c ^ 1);
    asm volatile("" ::: "memory");
    __builtin_amdgcn_s_barrier();
    asm volatile("s_waitcnt lgkmcnt(0)" ::: "memory");
    __builtin_amdgcn_s_setprio(1);
#pragma unroll
    for (int i = 0; i < 8; ++i) {
      acc[i][2] = __builtin_amdgcn_mfma_f32_16x16x32_bf16(a0[i], b2, acc[i][2], 0, 0, 0);
      acc[i][3] = __builtin_amdgcn_mfma_f32_16x16x32_bf16(a0[i], b3, acc[i][3], 0, 0, 0);
    }
    __builtin_amdgcn_s_setprio(0);

    // ---- P2: reads q2 ; lgkm0 BEFORE barrier (A handoff) ; MFMA q2
#pragma unroll
    for (int i = 0; i < 8; ++i)
      a1[i] = *(const bf16x8*)&pa[(wm * 128 + i * 16 + ro) * 64 + slot1 * 8];
    b0 = *(const bf16x8*)&pb[(wn * 64 + 0 * 16 + ro) * 64 + slot1 * 8];
    b1 = *(const bf16x8*)&pb[(wn * 64 + 1 * 16 + ro) * 64 + slot1 * 8];
    asm volatile("s_waitcnt lgkmcnt(0)" ::: "memory");
    __builtin_amdgcn_s_barrier();
    __builtin_amdgcn_s_setprio(1);
#pragma unroll
    for (int i = 0; i < 8; ++i) {
      acc[i][0] = __builtin_amdgcn_mfma_f32_16x16x32_bf16(a1[i], b0, acc[i][0], 0, 0, 0);
      acc[i][1] = __builtin_amdgcn_mfma_f32_16x16x32_bf16(a1[i], b1, acc[i][1], 0, 0, 0);
    }
    __builtin_amdgcn_s_setprio(0);

    // ---- P3: reads q3 ; stage A(T+2) -> buf c ; lgkm0+vmcnt BEFORE barrier ; MFMA q3
    b2 = *(const bf16x8*)&pb[(wn * 64 + 2 * 16 + ro) * 64 + slot1 * 8];
    b3 = *(const bf16x8*)&pb[(wn * 64 + 3 * 16 + ro) * 64 + slot1 * 8];
    if (T + 2 < 48) { stageA(T + 2, 0, c); stageA(T + 2, 1, c); }
    asm volatile("s_waitcnt lgkmcnt(0)" ::: "memory");
    if (T < 46)       asm volatile("s_waitcnt vmcnt(4)" ::: "memory");
    else if (T == 46) asm volatile("s_waitcnt vmcnt(0)" ::: "memory");
    __builtin_amdgcn_s_barrier();
    __builtin_amdgcn_s_setprio(1);
#pragma unroll
    for (int i = 0; i < 8; ++i) {
      acc[i][2] = __builtin_amdgcn_mfma_f32_16x16x32_bf16(a1[i], b2, acc[i][2], 0, 0, 0);
      acc[i][3] = __builtin_amdgcn_mfma_f32_16x16x32_bf16(a1[i], b3, acc[i][3], 0, 0, 0);
    }
    __builtin_amdgcn_s_setprio(0);

    // ---- bx epilogue: write C for this N-tile (stores drain in shadow), re-zero acc
    if ((T & 7) == 7) {
      const size_t cb = (size_t)(T >> 3) * 256;
#pragma unroll
      for (int i = 0; i < 8; ++i)
#pragma unroll
        for (int j = 0; j < 4; ++j)
#pragma unroll
          for (int r = 0; r < 4; ++r) {
            size_t row = m0 + wm * 128 + i * 16 + (kq << 2) + r;
            size_t col = cb + wn * 64 + j * 16 + ro;
            C[row * 1536 + col] = f2bf(acc[i][j][r]);
          }
#pragma unroll
      for (int i = 0; i < 8; ++i)
#pragma unroll
        for (int j = 0; j < 4; ++j)
          acc[i][j] = (f32x4){0.f, 0.f, 0.f, 0.f};
    }
  }
}

// ---------- 256x256, BK=64 (K=512 fixed), 8 waves, m201-ordered 4-phase pipeline ----------
// Used by the output GEMM (fp32 out, batched via strides).
template <bool BF16OUT>
__global__ __launch_bounds__(512, 1) void gemm256_8ph(const unsigned short* __restrict__ A,
                                                      const unsigned short* __restrict__ B,
                                                      void* __restrict__ Cv, int ldc,
                                                      size_t sA, size_t sB, size_t sC) {
  __shared__ unsigned short lA[2][256 * 64];
  __shared__ unsigned short lB[2][256 * 64];
  const int gx = gridDim.x, gy = gridDim.y;
  const int nwg = gx * gy * gridDim.z;
  int flat = blockIdx.x + gx * (blockIdx.y + gy * blockIdx.z);
  flat = (flat & 7) * (nwg >> 3) + (flat >> 3);
  const int bx = flat % gx;
  const int rem = flat / gx;
  const int by = rem % gy;
  const int bz = rem / gy;
  const size_t m0 = (size_t)by * 256;
  const size_t n0 = (size_t)bx * 256;
  A += (size_t)bz * sA;
  B += (size_t)bz * sB;

  const int t = threadIdx.x;
  const int lane = t & 63;
  const int wid = t >> 6;
  const int wm = wid >> 2, wn = wid & 3;
  const int ro = lane & 15, kq = lane >> 4;

  const int srow = t >> 3;
  const int sslot = t & 7;
  const int kslot = sslot ^ (srow & 7);

  auto stageA = [&](int kt, int h, int bbuf) {
    char* d = (char*)(&lA[bbuf][0]) + ((h * 128 + srow) * 64 + sslot * 8) * 2;
    const unsigned short* g = A + (m0 + h * 128 + srow) * 512 + kt * 64 + kslot * 8;
    gload16(g, d);
    gload16(g + (size_t)64 * 512, d + 64 * 128);
  };
  auto stageB = [&](int kt, int h, int bbuf) {
    char* d = (char*)(&lB[bbuf][0]) + ((h * 128 + srow) * 64 + sslot * 8) * 2;
    const unsigned short* g = B + (n0 + h * 128 + srow) * 512 + kt * 64 + kslot * 8;
    gload16(g, d);
    gload16(g + (size_t)64 * 512, d + 64 * 128);
  };

  f32x4 acc[8][4] = {};

  stageA(0, 0, 0); stageA(0, 1, 0);
  stageB(0, 0, 0); stageB(0, 1, 0);
  stageA(1, 0, 1); stageA(1, 1, 1);
  asm volatile("s_waitcnt vmcnt(4)" ::: "memory");
  __builtin_amdgcn_s_barrier();

#pragma unroll 1
  for (int kt = 0; kt < 8; ++kt) {
    const int c = kt & 1;
    const unsigned short* pa = &lA[c][0];
    const unsigned short* pb = &lB[c][0];
    const int slot0 = kq ^ (ro & 7);
    const int slot1 = (4 + kq) ^ (ro & 7);

    bf16x8 a0[8], a1[8], b0, b1, b2, b3;
#pragma unroll
    for (int i = 0; i < 8; ++i)
      a0[i] = *(const bf16x8*)&pa[(wm * 128 + i * 16 + ro) * 64 + slot0 * 8];
    b0 = *(const bf16x8*)&pb[(wn * 64 + 0 * 16 + ro) * 64 + slot0 * 8];
    b1 = *(const bf16x8*)&pb[(wn * 64 + 1 * 16 + ro) * 64 + slot0 * 8];
    if (kt + 1 < 8) stageB(kt + 1, 0, c ^ 1);
    asm volatile("" ::: "memory");
    __builtin_amdgcn_s_barrier();
    asm volatile("s_waitcnt lgkmcnt(0)" ::: "memory");
    __builtin_amdgcn_s_setprio(1);
#pragma unroll
    for (int i = 0; i < 8; ++i) {
      acc[i][0] = __builtin_amdgcn_mfma_f32_16x16x32_bf16(a0[i], b0, acc[i][0], 0, 0, 0);
      acc[i][1] = __builtin_amdgcn_mfma_f32_16x16x32_bf16(a0[i], b1, acc[i][1], 0, 0, 0);
    }
    __builtin_amdgcn_s_setprio(0);

    b2 = *(const bf16x8*)&pb[(wn * 64 + 2 * 16 + ro) * 64 + slot0 * 8];
    b3 = *(const bf16x8*)&pb[(wn * 64 + 3 * 16 + ro) * 64 + slot0 * 8];
    if (kt + 1 < 8) stageB(kt + 1, 1, c ^ 1);
    asm volatile("" ::: "memory");
    __builtin_amdgcn_s_barrier();
    asm volatile("s_waitcnt lgkmcnt(0)" ::: "memory");
    __builtin_amdgcn_s_setprio(1);
#pragma unroll
    for (int i = 0; i < 8; ++i) {
      acc[i][2] = __builtin_amdgcn_mfma_f32_16x16x32_bf16(a0[i], b2, acc[i][2], 0, 0, 0);
      acc[i][3] = __builtin_amdgcn_mfma_f32_16x16x32_bf16(a0[i], b3, acc[i][3], 0, 0, 0);
    }
    __builtin_amdgcn_s_setprio(0);

#pragma unroll
    for (int i = 0; i < 8; ++i)
      a1[i] = *(const bf16x8*)&pa[(wm * 128 + i * 16 + ro) * 64 + slot1 * 8];
    b0 = *(const bf16x8*)&pb[(wn * 64 + 0 * 16 + ro) * 64 + slot1 * 8];
    b1 = *(const bf16x8*)&pb[(wn * 64 + 1 * 16 + ro) * 64 + slot1 * 8];
    asm volatile("s_waitcnt lgkmcnt(0)" ::: "memory");
    __builtin_amdgcn_s_barrier();
    __builtin_amdgcn_s_setprio(1);
#pragma unroll
    for (int i = 0; i < 8; ++i) {
      acc[i][0] = __builtin_amdgcn_mfma_f32_16x16x32_bf16(a1[i], b0, acc[i][0], 0, 0, 0);
      acc[i][1] = __builtin_amdgcn_mfma_f32_16x16x32_bf16(a1[i], b1, acc[i][1], 0, 0, 0);
    }
    __builtin_amdgcn_s_setprio(0);

    b2 = *(const bf16x8*)&pb[(wn * 64 + 2 * 16 + ro) * 64 + slot1 * 8];
    b3 = *(const bf16x8*)&pb[(wn * 64 + 3 * 16 + ro) * 64 + slot1 * 8];
    if (kt + 2 < 8) { stageA(kt + 2, 0, c); stageA(kt + 2, 1, c); }
    asm volatile("s_waitcnt lgkmcnt(0)" ::: "memory");
    if (kt < 6)       asm volatile("s_waitcnt vmcnt(4)" ::: "memory");
    else if (kt == 6) asm volatile("s_waitcnt vmcnt(0)" ::: "memory");
    __builtin_amdgcn_s_barrier();
    __builtin_amdgcn_s_setprio(1);
#pragma unroll
    for (int i = 0; i < 8; ++i) {
      acc[i][2] = __builtin_amdgcn_mfma_f32_16x16x32_bf16(a1[i], b2, acc[i][2], 0, 0, 0);
      acc[i][3] = __builtin_amdgcn_mfma_f32_16x16x32_bf16(a1[i], b3, acc[i][3], 0, 0, 0);
    }
    __builtin_amdgcn_s_setprio(0);
  }

  if constexpr (BF16OUT) {
    unsigned short* C = (unsigned short*)Cv;
#pragma unroll
    for (int i = 0; i < 8; ++i)
#pragma unroll
      for (int j = 0; j < 4; ++j)
#pragma unroll
        for (int r = 0; r < 4; ++r) {
          size_t row = m0 + wm * 128 + i * 16 + (kq << 2) + r;
          size_t col = n0 + wn * 64 + j * 16 + ro;
          C[row * (size_t)ldc + col] = f2bf(acc[i][j][r]);
        }
  } else {
    float* C = (float*)Cv + (size_t)bz * sC;
#pragma unroll
    for (int i = 0; i < 8; ++i)
#pragma unroll
      for (int j = 0; j < 4; ++j)
#pragma unroll
        for (int r = 0; r < 4; ++r) {
          size_t row = m0 + wm * 128 + i * 16 + (kq << 2) + r;
          size_t col = n0 + wn * 64 + j * 16 + ro;
          C[row * (size_t)ldc + col] = acc[i][j][r];
        }
  }
}

// ---------- K2: dilated depthwise 3x3 conv + fused L2-norm (paired columns) ----------
struct Row4 { u32x2 v[4]; };

__global__ __launch_bounds__(256) void dwconv_norm(const unsigned short* __restrict__ Y,
                                                   const float* __restrict__ wdw,
                                                   unsigned short* __restrict__ Qb,
                                                   unsigned short* __restrict__ Kb,
                                                   unsigned short* __restrict__ Vb) {
  const int t = threadIdx.x, lane = t & 63, wv = t >> 6;
  const int bid = blockIdx.x;
  const int lbid = (bid & 7) * 384 + (bid >> 3);
  const int wid = lbid * 4 + wv;           // 12288 waves
  const int sub = wid & 255;
  const int grp = wid >> 8;                // 48 = 16 b * 3 parts
  const int pair = sub >> 3;               // 0..31
  const int par = (sub >> 2) & 1, chhalf = (sub >> 1) & 1, rowhalf = sub & 1;
  const int b = grp / 3, part = grp - b * 3;
  const int x0 = (pair >> 1) * 4 + (pair & 1);   // {0,1,4,5,...,61}; covers x0, x0+2
  const int c0 = chhalf * 256 + (lane >> 4) * 64 + (lane & 15) * 4;

  f32x2 wa[9], wb[9];
  {
    float qw[36];
    const float* wp = wdw + c0 * 9;
#pragma unroll
    for (int i = 0; i < 9; ++i) {
      f32x4 q = *(const f32x4*)(wp + i * 4);
      qw[i * 4 + 0] = q[0]; qw[i * 4 + 1] = q[1];
      qw[i * 4 + 2] = q[2]; qw[i * 4 + 3] = q[3];
    }
#pragma unroll
    for (int tap = 0; tap < 9; ++tap) {
      wa[tap] = (f32x2){qw[tap], qw[9 + tap]};
      wb[tap] = (f32x2){qw[18 + tap], qw[27 + tap]};
    }
  }

  const size_t ybase = (size_t)b * 4096 * 1536 + part * 512 + c0;
  const bool okm = (x0 >= 2), okp = (x0 + 4 <= 63);
  const int cm = okm ? x0 - 2 : x0;
  const int cp = okp ? x0 + 4 : x0;

  auto loadrow = [&](int yy) -> Row4 {
    Row4 r;
    const bool oky = ((unsigned)yy < 64u);
    const int yyc = oky ? yy : 0;
    const size_t rb = ybase + (size_t)(yyc * 64) * 1536;
    u32x2 a = *(const u32x2*)(Y + rb + (size_t)cm * 1536);
    u32x2 c = *(const u32x2*)(Y + rb + (size_t)x0 * 1536);
    u32x2 d = *(const u32x2*)(Y + rb + (size_t)(x0 + 2) * 1536);
    u32x2 e = *(const u32x2*)(Y + rb + (size_t)cp * 1536);
    r.v[0] = a & ((oky && okm) ? 0xFFFFFFFFu : 0u);
    r.v[1] = c & (oky ? 0xFFFFFFFFu : 0u);
    r.v[2] = d & (oky ? 0xFFFFFFFFu : 0u);
    r.v[3] = e & ((oky && okp) ? 0xFFFFFFFFu : 0u);
    return r;
  };

  const int y0 = par + rowhalf * 32;
  Row4 W[3];
  W[0] = loadrow(y0 - 2);
  W[1] = loadrow(y0);
  W[2] = loadrow(y0 + 2);

  unsigned short* dstA = (part == 0 ? Qb : (part == 1 ? Kb : Vb)) +
                         ((size_t)b * 4096 + x0) * 512 + c0;
  unsigned short* dstB = dstA + (size_t)2 * 512;   // col x0+2

#pragma unroll
  for (int i = 0; i < 16; ++i) {
    const int y = y0 + 2 * i;
    f32x2 A01 = (f32x2){0.f, 0.f}, A23 = (f32x2){0.f, 0.f};
    f32x2 B01 = (f32x2){0.f, 0.f}, B23 = (f32x2){0.f, 0.f};
#pragma unroll
    for (int r = 0; r < 3; ++r) {
      const Row4& R = W[(i + r) % 3];
#pragma unroll
      for (int xt = 0; xt < 4; ++xt) {
        const u32x2 v = R.v[xt];
        f32x2 lo = (f32x2){asf(v[0] << 16), asf(v[0] & 0xFFFF0000u)};
        f32x2 hi = (f32x2){asf(v[1] << 16), asf(v[1] & 0xFFFF0000u)};
        if (xt < 3) {
          const int tap = r * 3 + xt;
          A01 += lo * wa[tap];
          A23 += hi * wb[tap];
        }
        if (xt >= 1) {
          const int tap = r * 3 + xt - 1;
          B01 += lo * wa[tap];
          B23 += hi * wb[tap];
        }
      }
    }
    if (part < 2) {
      f32x2 sa = A01 * A01 + A23 * A23;
      f32x2 sb = B01 * B01 + B23 * B23;
      float ssa = sa[0] + sa[1];
      float ssb = sb[0] + sb[1];
#pragma unroll
      for (int m = 1; m <= 8; m <<= 1) {
        ssa += __shfl_xor(ssa, m);
        ssb += __shfl_xor(ssb, m);
      }
      const float ra = 1.f / fmaxf(sqrtf(ssa), 1e-12f);
      const float rb2 = 1.f / fmaxf(sqrtf(ssb), 1e-12f);
      A01 *= ra; A23 *= ra;
      B01 *= rb2; B23 *= rb2;
    }
    unsigned int p0, p1, q0, q1;
    asm("v_cvt_pk_bf16_f32 %0, %1, %2" : "=v"(p0) : "v"(A01[0]), "v"(A01[1]));
    asm("v_cvt_pk_bf16_f32 %0, %1, %2" : "=v"(p1) : "v"(A23[0]), "v"(A23[1]));
    asm("v_cvt_pk_bf16_f32 %0, %1, %2" : "=v"(q0) : "v"(B01[0]), "v"(B01[1]));
    asm("v_cvt_pk_bf16_f32 %0, %1, %2" : "=v"(q1) : "v"(B23[0]), "v"(B23[1]));
    u32x2 pkA; pkA[0] = p0; pkA[1] = p1;
    u32x2 pkB; pkB[0] = q0; pkB[1] = q1;
    *(u32x2*)(dstA + (size_t)y * 64 * 512) = pkA;
    *(u32x2*)(dstB + (size_t)y * 64 * 512) = pkB;
    if (i < 15) W[i % 3] = loadrow(y + 4);
  }
}

// ---------- K3: partial S[d,e] = sum_n qn[d,n]*kn[e,n], per (b,h), split-n ----------
__global__ __launch_bounds__(256) void attn_partial(const unsigned short* __restrict__ Qb,
                                                    const unsigned short* __restrict__ Kb,
                                                    float* __restrict__ Spart) {
  __shared__ unsigned short sQ[4][64][72];
  __shared__ unsigned short sK[4][64][72];
  const int t = threadIdx.x, lane = t & 63, wv = t >> 6;
  const int bh = blockIdx.x >> 2;
  const int s = (blockIdx.x & 3) * 4 + wv;
  const int b = bh >> 3, h = bh & 7;
  const unsigned short* qbase = Qb + ((size_t)b * 4096) * 512 + h * 64;
  const unsigned short* kbase = Kb + ((size_t)b * 4096) * 512 + h * 64;
  f32x4 acc[4][4] = {};
  for (int ch = 0; ch < 4; ++ch) {
    const int n0 = s * 256 + ch * 64;
    const unsigned short* qp = qbase + (size_t)(n0 + lane) * 512;
    const unsigned short* kp = kbase + (size_t)(n0 + lane) * 512;
    ushort8 qv[8], kv[8];
#pragma unroll
    for (int v = 0; v < 8; ++v) qv[v] = *(const ushort8*)(qp + v * 8);
#pragma unroll
    for (int v = 0; v < 8; ++v) kv[v] = *(const ushort8*)(kp + v * 8);
#pragma unroll
    for (int v = 0; v < 8; ++v)
#pragma unroll
      for (int j = 0; j < 8; ++j) {
        sQ[wv][v * 8 + j][lane] = qv[v][j];
        sK[wv][v * 8 + j][lane] = kv[v][j];
      }
    __syncthreads();
    const int ro = lane & 15, ko = (lane >> 4) * 8;
#pragma unroll
    for (int ks = 0; ks < 2; ++ks) {
      bf16x8 af[4], bv[4];
#pragma unroll
      for (int i = 0; i < 4; ++i) af[i] = *(const bf16x8*)&sQ[wv][i * 16 + ro][ks * 32 + ko];
#pragma unroll
      for (int i = 0; i < 4; ++i) bv[i] = *(const bf16x8*)&sK[wv][i * 16 + ro][ks * 32 + ko];
#pragma unroll
      for (int i = 0; i < 4; ++i)
#pragma unroll
        for (int j = 0; j < 4; ++j)
          acc[i][j] = __builtin_amdgcn_mfma_f32_16x16x32_bf16(af[i], bv[j], acc[i][j], 0, 0, 0);
    }
    __syncthreads();
  }
  float* dst = Spart + ((size_t)bh * 16 + s) * 4096;
#pragma unroll
  for (int i = 0; i < 4; ++i)
#pragma unroll
    for (int j = 0; j < 4; ++j)
#pragma unroll
      for (int r = 0; r < 4; ++r) {
        int d = i * 16 + ((lane >> 4) << 2) + r;
        int e = j * 16 + (lane & 15);
        dst[d * 64 + e] = acc[i][j][r];
      }
}

// ---------- K4: combine partials, scale by 1/temp, softmax over e, write bf16 attn ----------
__global__ __launch_bounds__(256) void softmax_attn(const float* __restrict__ Spart,
                                                    const float* __restrict__ tptr,
                                                    unsigned short* __restrict__ attn) {
  const int bh = blockIdx.x, t = threadIdx.x;
  const int d = t >> 2, eb = (t & 3) << 4;
  const float inv_t = 1.f / fmaxf(tptr[0], 1e-5f);
  float v[16];
#pragma unroll
  for (int i = 0; i < 16; ++i) v[i] = 0.f;
  for (int s = 0; s < 16; ++s) {
    const f32x4* p = (const f32x4*)(Spart + ((size_t)bh * 16 + s) * 4096 + d * 64 + eb);
#pragma unroll
    for (int i = 0; i < 4; ++i) {
      f32x4 q = p[i];
      v[i * 4 + 0] += q[0]; v[i * 4 + 1] += q[1];
      v[i * 4 + 2] += q[2]; v[i * 4 + 3] += q[3];
    }
  }
  float mx = -1e30f;
#pragma unroll
  for (int i = 0; i < 16; ++i) { v[i] *= inv_t; mx = fmaxf(mx, v[i]); }
  mx = fmaxf(mx, __shfl_xor(mx, 1));
  mx = fmaxf(mx, __shfl_xor(mx, 2));
  float sm = 0.f;
#pragma unroll
  for (int i = 0; i < 16; ++i) { v[i] = __expf(v[i] - mx); sm += v[i]; }
  sm += __shfl_xor(sm, 1);
  sm += __shfl_xor(sm, 2);
  const float r = 1.f / sm;
  ushort8 pk0, pk1;
#pragma unroll
  for (int i = 0; i < 8; ++i) { pk0[i] = f2bf(v[i] * r); pk1[i] = f2bf(v[8 + i] * r); }
  ushort8* dst = (ushort8*)(attn + (size_t)bh * 4096 + d * 64 + eb);
  dst[0] = pk0; dst[1] = pk1;
}

// ---------- K5: w2[b] = w_out @ blockdiag(attn_b)  (per (b,h): 512x64, K=64) ----------
__global__ __launch_bounds__(256) void make_w2(const unsigned short* __restrict__ attn,
                                               const float* __restrict__ w_out,
                                               unsigned short* __restrict__ w2) {
  __shared__ float sA[4096];
  const int bx = blockIdx.x;
  const int bh = bx >> 1, half = bx & 1;
  const int b = bh >> 3, h = bh & 7;
  const int t = threadIdx.x;
  for (int i = t; i < 4096; i += 256) sA[i] = bf2f(attn[(size_t)bh * 4096 + i]);
  __syncthreads();
  const int o = half * 256 + t;
  float w[64];
  const float* wp = w_out + (size_t)o * 512 + h * 64;
#pragma unroll
  for (int i = 0; i < 64; i += 4) {
    f32x4 q = *(const f32x4*)(wp + i);
    w[i] = q[0]; w[i + 1] = q[1]; w[i + 2] = q[2]; w[i + 3] = q[3];
  }
  unsigned short* dst = w2 + ((size_t)b * 512 + o) * 512 + h * 64;
#pragma unroll 1
  for (int eg = 0; eg < 8; ++eg) {
    ushort8 pk;
#pragma unroll
    for (int ee = 0; ee < 8; ++ee) {
      const int e = eg * 8 + ee;
      float acc = 0.f;
#pragma unroll
      for (int dd = 0; dd < 64; ++dd) acc += w[dd] * sA[dd * 64 + e];
      pk[ee] = f2bf(acc);
    }
    *(ushort8*)(dst + eg * 8) = pk;
  }
}

extern "C" void kernel_launch(void* const* d_in, const int* in_sizes, int n_in,
                              void* d_out, int out_size, void* d_ws, size_t ws_size,
                              hipStream_t stream) {
  const float* x     = (const float*)d_in[0];
  const float* w_qkv = (const float*)d_in[1];
  const float* w_dw  = (const float*)d_in[2];
  const float* w_out = (const float*)d_in[3];
  const float* temp  = (const float*)d_in[4];
  float* out = (float*)d_out;

  char* ws = (char*)d_ws;
  const size_t MB = 1024 * 1024;
  unsigned short* Xt    = (unsigned short*)(ws);            // 64MB  (dead after gemm1)
  float*          Spart = (float*)(ws);                     // 32MB  (reuses Xt region)
  unsigned short* attn  = (unsigned short*)(ws + 32 * MB);  // 1MB
  unsigned short* w2    = (unsigned short*)(ws + 33 * MB);  // 8MB
  unsigned short* Y     = (unsigned short*)(ws + 64 * MB);  // 192MB qkv pre-conv, channels-last
  unsigned short* Qb    = (unsigned short*)(ws + 256 * MB); // 64MB
  unsigned short* Kb    = (unsigned short*)(ws + 320 * MB); // 64MB
  unsigned short* Vb    = (unsigned short*)(ws + 384 * MB); // 64MB
  unsigned short* Wq    = (unsigned short*)(ws + 448 * MB); // 1.5MB

  cvt_f32_bf16<<<3072, 256, 0, stream>>>(w_qkv, Wq, 1536 * 512);
  transpose_x<<<dim3(64, 8, 16), 256, 0, stream>>>(x, Xt);
  // Y[(b*4096+n), o] = sum_c Xt[(b*4096+n), c] * Wq[o, c]   M=65536 N=1536 K=512
  gemm_qkv_pers<<<256, 512, 0, stream>>>(Xt, Wq, Y);
  dwconv_norm<<<3072, 256, 0, stream>>>(Y, w_dw, Qb, Kb, Vb);
  attn_partial<<<512, 256, 0, stream>>>(Qb, Kb, Spart);
  softmax_attn<<<128, 256, 0, stream>>>(Spart, temp, attn);
  make_w2<<<256, 256, 0, stream>>>(attn, w_out, w2);
  // out[b, o, p] = sum_c' w2[b, o, c'] * Vb[b, p, c']   per b: M=512 N=4096 K=512
  gemm256_8ph<false><<<dim3(16, 2, 16), 512, 0, stream>>>(
      w2, Vb, out, 4096,
      (size_t)512 * 512, (size_t)4096 * 512, (size_t)512 * 4096);
}

// Round 17
// 401.991 us; speedup vs baseline: 1.0966x; 1.0966x over previous
//
#include <hip/hip_runtime.h>

typedef __attribute__((ext_vector_type(8))) short bf16x8;
typedef __attribute__((ext_vector_type(8))) unsigned short ushort8;
typedef __attribute__((ext_vector_type(4))) float f32x4;
typedef __attribute__((ext_vector_type(2))) float f32x2;
typedef __attribute__((ext_vector_type(4))) unsigned int u32x4;
typedef __attribute__((ext_vector_type(2))) unsigned int u32x2;

__device__ __forceinline__ float bf2f(unsigned short u) {
  union { unsigned int i; float f; } v; v.i = ((unsigned int)u) << 16; return v.f;
}
__device__ __forceinline__ float asf(unsigned int u) {
  union { unsigned int i; float f; } v; v.i = u; return v.f;
}
__device__ __forceinline__ unsigned short f2bf(float f) {
  union { float f; unsigned int i; } v; v.f = f;
  unsigned int u = v.i;
  return (unsigned short)((u + 0x7FFFu + ((u >> 16) & 1u)) >> 16);
}
__device__ __forceinline__ void gload16(const void* g, void* l) {
  __builtin_amdgcn_global_load_lds(
      (const __attribute__((address_space(1))) void*)g,
      (__attribute__((address_space(3))) void*)l, 16, 0, 0);
}

// ---------- K-1: fp32 -> bf16 convert (w_qkv) ----------
__global__ __launch_bounds__(256) void cvt_f32_bf16(const float* __restrict__ s,
                                                    unsigned short* __restrict__ d, int n) {
  int i = blockIdx.x * 256 + threadIdx.x;
  if (i < n) d[i] = f2bf(s[i]);
}

// ---------- K0: x (B,C,N) fp32 -> Xt (B,N,C) bf16, LDS tiled, packed u32 stores ----------
__global__ __launch_bounds__(256) void transpose_x(const float* __restrict__ x,
                                                   unsigned short* __restrict__ xt) {
  __shared__ float tile[64][65];
  const int b = blockIdx.z, ct = blockIdx.y, nt = blockIdx.x;
  const int t = threadIdx.x;
  const int r0 = t >> 6, col = t & 63;
  const float* src = x + ((size_t)b * 512 + ct * 64) * 4096 + nt * 64;
#pragma unroll
  for (int i = 0; i < 16; ++i) {
    int r = i * 4 + r0;
    tile[r][col] = src[(size_t)r * 4096 + col];
  }
  __syncthreads();
  unsigned short* dst = xt + ((size_t)b * 4096 + nt * 64) * 512 + ct * 64;
  const int c2 = (t & 31) * 2;
  const int nsub = t >> 5;   // 0..7
#pragma unroll
  for (int i = 0; i < 8; ++i) {
    int n = i * 8 + nsub;
    unsigned int p;
    asm("v_cvt_pk_bf16_f32 %0, %1, %2" : "=v"(p) : "v"(tile[c2][n]), "v"(tile[c2 + 1][n]));
    *(unsigned int*)(dst + (size_t)n * 512 + c2) = p;
  }
}

// ---------- 256x256, BK=64 (K=512 fixed), 8 waves, m201-ordered 4-phase pipeline ----------
// Shared by QKV GEMM (bf16 out) and output GEMM (fp32 out, batched via strides).
template <bool BF16OUT>
__global__ __launch_bounds__(512, 1) void gemm256_8ph(const unsigned short* __restrict__ A,
                                                      const unsigned short* __restrict__ B,
                                                      void* __restrict__ Cv, int ldc,
                                                      size_t sA, size_t sB, size_t sC) {
  __shared__ unsigned short lA[2][256 * 64];
  __shared__ unsigned short lB[2][256 * 64];
  const int gx = gridDim.x, gy = gridDim.y;
  const int nwg = gx * gy * gridDim.z;
  int flat = blockIdx.x + gx * (blockIdx.y + gy * blockIdx.z);
  flat = (flat & 7) * (nwg >> 3) + (flat >> 3);
  const int bx = flat % gx;
  const int rem = flat / gx;
  const int by = rem % gy;
  const int bz = rem / gy;
  const size_t m0 = (size_t)by * 256;
  const size_t n0 = (size_t)bx * 256;
  A += (size_t)bz * sA;
  B += (size_t)bz * sB;

  const int t = threadIdx.x;
  const int lane = t & 63;
  const int wid = t >> 6;
  const int wm = wid >> 2, wn = wid & 3;  // 2 x 4 waves, each owns 128x64 of C
  const int ro = lane & 15, kq = lane >> 4;

  const int srow = t >> 3;                // 0..63
  const int sslot = t & 7;
  const int kslot = sslot ^ (srow & 7);

  auto stageA = [&](int kt, int h, int bbuf) {
    char* d = (char*)(&lA[bbuf][0]) + ((h * 128 + srow) * 64 + sslot * 8) * 2;
    const unsigned short* g = A + (m0 + h * 128 + srow) * 512 + kt * 64 + kslot * 8;
    gload16(g, d);
    gload16(g + (size_t)64 * 512, d + 64 * 128);
  };
  auto stageB = [&](int kt, int h, int bbuf) {
    char* d = (char*)(&lB[bbuf][0]) + ((h * 128 + srow) * 64 + sslot * 8) * 2;
    const unsigned short* g = B + (n0 + h * 128 + srow) * 512 + kt * 64 + kslot * 8;
    gload16(g, d);
    gload16(g + (size_t)64 * 512, d + 64 * 128);
  };

  f32x4 acc[8][4] = {};

  // prologue: A(0), B(0) -> buf0; A(1) -> buf1   (12 loads in flight)
  stageA(0, 0, 0); stageA(0, 1, 0);
  stageB(0, 0, 0); stageB(0, 1, 0);
  stageA(1, 0, 1); stageA(1, 1, 1);
  asm volatile("s_waitcnt vmcnt(4)" ::: "memory");   // A(0)+B(0) landed
  __builtin_amdgcn_s_barrier();

#pragma unroll 1
  for (int kt = 0; kt < 8; ++kt) {
    const int c = kt & 1;
    const unsigned short* pa = &lA[c][0];
    const unsigned short* pb = &lB[c][0];
    const int slot0 = kq ^ (ro & 7);        // kk=0
    const int slot1 = (4 + kq) ^ (ro & 7);  // kk=1

    // ---- P0: reads q0 ; stage B(t+1)h0 ; barrier ; lgkm0 ; MFMA q0
    bf16x8 a0[8], a1[8], b0, b1, b2, b3;
#pragma unroll
    for (int i = 0; i < 8; ++i)
      a0[i] = *(const bf16x8*)&pa[(wm * 128 + i * 16 + ro) * 64 + slot0 * 8];
    b0 = *(const bf16x8*)&pb[(wn * 64 + 0 * 16 + ro) * 64 + slot0 * 8];
    b1 = *(const bf16x8*)&pb[(wn * 64 + 1 * 16 + ro) * 64 + slot0 * 8];
    if (kt + 1 < 8) stageB(kt + 1, 0, c ^ 1);
    asm volatile("" ::: "memory");
    __builtin_amdgcn_s_barrier();
    asm volatile("s_waitcnt lgkmcnt(0)" ::: "memory");
    __builtin_amdgcn_s_setprio(1);
#pragma unroll
    for (int i = 0; i < 8; ++i) {
      acc[i][0] = __builtin_amdgcn_mfma_f32_16x16x32_bf16(a0[i], b0, acc[i][0], 0, 0, 0);
      acc[i][1] = __builtin_amdgcn_mfma_f32_16x16x32_bf16(a0[i], b1, acc[i][1], 0, 0, 0);
    }
    __builtin_amdgcn_s_setprio(0);

    // ---- P1: reads q1 ; stage B(t+1)h1 ; barrier ; lgkm0 ; MFMA q1
    b2 = *(const bf16x8*)&pb[(wn * 64 + 2 * 16 + ro) * 64 + slot0 * 8];
    b3 = *(const bf16x8*)&pb[(wn * 64 + 3 * 16 + ro) * 64 + slot0 * 8];
    if (kt + 1 < 8) stageB(kt + 1, 1, c ^ 1);
    asm volatile("" ::: "memory");
    __builtin_amdgcn_s_barrier();
    asm volatile("s_waitcnt lgkmcnt(0)" ::: "memory");
    __builtin_amdgcn_s_setprio(1);
#pragma unroll
    for (int i = 0; i < 8; ++i) {
      acc[i][2] = __builtin_amdgcn_mfma_f32_16x16x32_bf16(a0[i], b2, acc[i][2], 0, 0, 0);
      acc[i][3] = __builtin_amdgcn_mfma_f32_16x16x32_bf16(a0[i], b3, acc[i][3], 0, 0, 0);
    }
    __builtin_amdgcn_s_setprio(0);

    // ---- P2: reads q2 ; lgkm0 BEFORE barrier (A handoff) ; MFMA q2
#pragma unroll
    for (int i = 0; i < 8; ++i)
      a1[i] = *(const bf16x8*)&pa[(wm * 128 + i * 16 + ro) * 64 + slot1 * 8];
    b0 = *(const bf16x8*)&pb[(wn * 64 + 0 * 16 + ro) * 64 + slot1 * 8];
    b1 = *(const bf16x8*)&pb[(wn * 64 + 1 * 16 + ro) * 64 + slot1 * 8];
    asm volatile("s_waitcnt lgkmcnt(0)" ::: "memory");
    __builtin_amdgcn_s_barrier();
    __builtin_amdgcn_s_setprio(1);
#pragma unroll
    for (int i = 0; i < 8; ++i) {
      acc[i][0] = __builtin_amdgcn_mfma_f32_16x16x32_bf16(a1[i], b0, acc[i][0], 0, 0, 0);
      acc[i][1] = __builtin_amdgcn_mfma_f32_16x16x32_bf16(a1[i], b1, acc[i][1], 0, 0, 0);
    }
    __builtin_amdgcn_s_setprio(0);

    // ---- P3: reads q3 ; stage A(t+2) -> buf c ; lgkm0+vmcnt BEFORE barrier ; MFMA q3
    b2 = *(const bf16x8*)&pb[(wn * 64 + 2 * 16 + ro) * 64 + slot1 * 8];
    b3 = *(const bf16x8*)&pb[(wn * 64 + 3 * 16 + ro) * 64 + slot1 * 8];
    if (kt + 2 < 8) { stageA(kt + 2, 0, c); stageA(kt + 2, 1, c); }
    asm volatile("s_waitcnt lgkmcnt(0)" ::: "memory");
    if (kt < 6)       asm volatile("s_waitcnt vmcnt(4)" ::: "memory");
    else if (kt == 6) asm volatile("s_waitcnt vmcnt(0)" ::: "memory");
    __builtin_amdgcn_s_barrier();
    __builtin_amdgcn_s_setprio(1);
#pragma unroll
    for (int i = 0; i < 8; ++i) {
      acc[i][2] = __builtin_amdgcn_mfma_f32_16x16x32_bf16(a1[i], b2, acc[i][2], 0, 0, 0);
      acc[i][3] = __builtin_amdgcn_mfma_f32_16x16x32_bf16(a1[i], b3, acc[i][3], 0, 0, 0);
    }
    __builtin_amdgcn_s_setprio(0);
  }

  if constexpr (BF16OUT) {
    unsigned short* C = (unsigned short*)Cv;
#pragma unroll
    for (int i = 0; i < 8; ++i)
#pragma unroll
      for (int j = 0; j < 4; ++j)
#pragma unroll
        for (int r = 0; r < 4; ++r) {
          size_t row = m0 + wm * 128 + i * 16 + (kq << 2) + r;
          size_t col = n0 + wn * 64 + j * 16 + ro;
          C[row * (size_t)ldc + col] = f2bf(acc[i][j][r]);
        }
  } else {
    float* C = (float*)Cv + (size_t)bz * sC;
#pragma unroll
    for (int i = 0; i < 8; ++i)
#pragma unroll
      for (int j = 0; j < 4; ++j)
#pragma unroll
        for (int r = 0; r < 4; ++r) {
          size_t row = m0 + wm * 128 + i * 16 + (kq << 2) + r;
          size_t col = n0 + wn * 64 + j * 16 + ro;
          C[row * (size_t)ldc + col] = acc[i][j][r];
        }
  }
}

// ---------- K2: dilated depthwise 3x3 conv + fused L2-norm (paired columns) ----------
struct Row4 { u32x2 v[4]; };

__global__ __launch_bounds__(256) void dwconv_norm(const unsigned short* __restrict__ Y,
                                                   const float* __restrict__ wdw,
                                                   unsigned short* __restrict__ Qb,
                                                   unsigned short* __restrict__ Kb,
                                                   unsigned short* __restrict__ Vb) {
  const int t = threadIdx.x, lane = t & 63, wv = t >> 6;
  const int bid = blockIdx.x;
  const int lbid = (bid & 7) * 384 + (bid >> 3);
  const int wid = lbid * 4 + wv;           // 12288 waves
  const int sub = wid & 255;
  const int grp = wid >> 8;                // 48 = 16 b * 3 parts
  const int pair = sub >> 3;               // 0..31
  const int par = (sub >> 2) & 1, chhalf = (sub >> 1) & 1, rowhalf = sub & 1;
  const int b = grp / 3, part = grp - b * 3;
  const int x0 = (pair >> 1) * 4 + (pair & 1);   // {0,1,4,5,...,61}; covers x0, x0+2
  const int c0 = chhalf * 256 + (lane >> 4) * 64 + (lane & 15) * 4;

  f32x2 wa[9], wb[9];
  {
    float qw[36];
    const float* wp = wdw + c0 * 9;
#pragma unroll
    for (int i = 0; i < 9; ++i) {
      f32x4 q = *(const f32x4*)(wp + i * 4);
      qw[i * 4 + 0] = q[0]; qw[i * 4 + 1] = q[1];
      qw[i * 4 + 2] = q[2]; qw[i * 4 + 3] = q[3];
    }
#pragma unroll
    for (int tap = 0; tap < 9; ++tap) {
      wa[tap] = (f32x2){qw[tap], qw[9 + tap]};
      wb[tap] = (f32x2){qw[18 + tap], qw[27 + tap]};
    }
  }

  const size_t ybase = (size_t)b * 4096 * 1536 + part * 512 + c0;
  const bool okm = (x0 >= 2), okp = (x0 + 4 <= 63);
  const int cm = okm ? x0 - 2 : x0;
  const int cp = okp ? x0 + 4 : x0;

  auto loadrow = [&](int yy) -> Row4 {
    Row4 r;
    const bool oky = ((unsigned)yy < 64u);
    const int yyc = oky ? yy : 0;
    const size_t rb = ybase + (size_t)(yyc * 64) * 1536;
    u32x2 a = *(const u32x2*)(Y + rb + (size_t)cm * 1536);
    u32x2 c = *(const u32x2*)(Y + rb + (size_t)x0 * 1536);
    u32x2 d = *(const u32x2*)(Y + rb + (size_t)(x0 + 2) * 1536);
    u32x2 e = *(const u32x2*)(Y + rb + (size_t)cp * 1536);
    r.v[0] = a & ((oky && okm) ? 0xFFFFFFFFu : 0u);
    r.v[1] = c & (oky ? 0xFFFFFFFFu : 0u);
    r.v[2] = d & (oky ? 0xFFFFFFFFu : 0u);
    r.v[3] = e & ((oky && okp) ? 0xFFFFFFFFu : 0u);
    return r;
  };

  const int y0 = par + rowhalf * 32;
  Row4 W[3];
  W[0] = loadrow(y0 - 2);
  W[1] = loadrow(y0);
  W[2] = loadrow(y0 + 2);

  unsigned short* dstA = (part == 0 ? Qb : (part == 1 ? Kb : Vb)) +
                         ((size_t)b * 4096 + x0) * 512 + c0;
  unsigned short* dstB = dstA + (size_t)2 * 512;   // col x0+2

#pragma unroll
  for (int i = 0; i < 16; ++i) {
    const int y = y0 + 2 * i;
    f32x2 A01 = (f32x2){0.f, 0.f}, A23 = (f32x2){0.f, 0.f};
    f32x2 B01 = (f32x2){0.f, 0.f}, B23 = (f32x2){0.f, 0.f};
#pragma unroll
    for (int r = 0; r < 3; ++r) {
      const Row4& R = W[(i + r) % 3];
#pragma unroll
      for (int xt = 0; xt < 4; ++xt) {
        const u32x2 v = R.v[xt];
        f32x2 lo = (f32x2){asf(v[0] << 16), asf(v[0] & 0xFFFF0000u)};
        f32x2 hi = (f32x2){asf(v[1] << 16), asf(v[1] & 0xFFFF0000u)};
        if (xt < 3) {
          const int tap = r * 3 + xt;
          A01 += lo * wa[tap];
          A23 += hi * wb[tap];
        }
        if (xt >= 1) {
          const int tap = r * 3 + xt - 1;
          B01 += lo * wa[tap];
          B23 += hi * wb[tap];
        }
      }
    }
    if (part < 2) {
      f32x2 sa = A01 * A01 + A23 * A23;
      f32x2 sb = B01 * B01 + B23 * B23;
      float ssa = sa[0] + sa[1];
      float ssb = sb[0] + sb[1];
#pragma unroll
      for (int m = 1; m <= 8; m <<= 1) {
        ssa += __shfl_xor(ssa, m);
        ssb += __shfl_xor(ssb, m);
      }
      const float ra = 1.f / fmaxf(sqrtf(ssa), 1e-12f);
      const float rb2 = 1.f / fmaxf(sqrtf(ssb), 1e-12f);
      A01 *= ra; A23 *= ra;
      B01 *= rb2; B23 *= rb2;
    }
    unsigned int p0, p1, q0, q1;
    asm("v_cvt_pk_bf16_f32 %0, %1, %2" : "=v"(p0) : "v"(A01[0]), "v"(A01[1]));
    asm("v_cvt_pk_bf16_f32 %0, %1, %2" : "=v"(p1) : "v"(A23[0]), "v"(A23[1]));
    asm("v_cvt_pk_bf16_f32 %0, %1, %2" : "=v"(q0) : "v"(B01[0]), "v"(B01[1]));
    asm("v_cvt_pk_bf16_f32 %0, %1, %2" : "=v"(q1) : "v"(B23[0]), "v"(B23[1]));
    u32x2 pkA; pkA[0] = p0; pkA[1] = p1;
    u32x2 pkB; pkB[0] = q0; pkB[1] = q1;
    *(u32x2*)(dstA + (size_t)y * 64 * 512) = pkA;
    *(u32x2*)(dstB + (size_t)y * 64 * 512) = pkB;
    if (i < 15) W[i % 3] = loadrow(y + 4);
  }
}

// ---------- K3: partial S[d,e] = sum_n qn[d,n]*kn[e,n], per (b,h), split-n ----------
__global__ __launch_bounds__(256) void attn_partial(const unsigned short* __restrict__ Qb,
                                                    const unsigned short* __restrict__ Kb,
                                                    float* __restrict__ Spart) {
  __shared__ unsigned short sQ[4][64][72];
  __shared__ unsigned short sK[4][64][72];
  const int t = threadIdx.x, lane = t & 63, wv = t >> 6;
  const int bh = blockIdx.x >> 2;
  const int s = (blockIdx.x & 3) * 4 + wv;
  const int b = bh >> 3, h = bh & 7;
  const unsigned short* qbase = Qb + ((size_t)b * 4096) * 512 + h * 64;
  const unsigned short* kbase = Kb + ((size_t)b * 4096) * 512 + h * 64;
  f32x4 acc[4][4] = {};
  for (int ch = 0; ch < 4; ++ch) {
    const int n0 = s * 256 + ch * 64;
    const unsigned short* qp = qbase + (size_t)(n0 + lane) * 512;
    const unsigned short* kp = kbase + (size_t)(n0 + lane) * 512;
    ushort8 qv[8], kv[8];
#pragma unroll
    for (int v = 0; v < 8; ++v) qv[v] = *(const ushort8*)(qp + v * 8);
#pragma unroll
    for (int v = 0; v < 8; ++v) kv[v] = *(const ushort8*)(kp + v * 8);
#pragma unroll
    for (int v = 0; v < 8; ++v)
#pragma unroll
      for (int j = 0; j < 8; ++j) {
        sQ[wv][v * 8 + j][lane] = qv[v][j];
        sK[wv][v * 8 + j][lane] = kv[v][j];
      }
    __syncthreads();
    const int ro = lane & 15, ko = (lane >> 4) * 8;
#pragma unroll
    for (int ks = 0; ks < 2; ++ks) {
      bf16x8 af[4], bv[4];
#pragma unroll
      for (int i = 0; i < 4; ++i) af[i] = *(const bf16x8*)&sQ[wv][i * 16 + ro][ks * 32 + ko];
#pragma unroll
      for (int i = 0; i < 4; ++i) bv[i] = *(const bf16x8*)&sK[wv][i * 16 + ro][ks * 32 + ko];
#pragma unroll
      for (int i = 0; i < 4; ++i)
#pragma unroll
        for (int j = 0; j < 4; ++j)
          acc[i][j] = __builtin_amdgcn_mfma_f32_16x16x32_bf16(af[i], bv[j], acc[i][j], 0, 0, 0);
    }
    __syncthreads();
  }
  float* dst = Spart + ((size_t)bh * 16 + s) * 4096;
#pragma unroll
  for (int i = 0; i < 4; ++i)
#pragma unroll
    for (int j = 0; j < 4; ++j)
#pragma unroll
      for (int r = 0; r < 4; ++r) {
        int d = i * 16 + ((lane >> 4) << 2) + r;
        int e = j * 16 + (lane & 15);
        dst[d * 64 + e] = acc[i][j][r];
      }
}

// ---------- K4: combine partials, scale by 1/temp, softmax over e, write bf16 attn ----------
__global__ __launch_bounds__(256) void softmax_attn(const float* __restrict__ Spart,
                                                    const float* __restrict__ tptr,
                                                    unsigned short* __restrict__ attn) {
  const int bh = blockIdx.x, t = threadIdx.x;
  const int d = t >> 2, eb = (t & 3) << 4;
  const float inv_t = 1.f / fmaxf(tptr[0], 1e-5f);
  float v[16];
#pragma unroll
  for (int i = 0; i < 16; ++i) v[i] = 0.f;
  for (int s = 0; s < 16; ++s) {
    const f32x4* p = (const f32x4*)(Spart + ((size_t)bh * 16 + s) * 4096 + d * 64 + eb);
#pragma unroll
    for (int i = 0; i < 4; ++i) {
      f32x4 q = p[i];
      v[i * 4 + 0] += q[0]; v[i * 4 + 1] += q[1];
      v[i * 4 + 2] += q[2]; v[i * 4 + 3] += q[3];
    }
  }
  float mx = -1e30f;
#pragma unroll
  for (int i = 0; i < 16; ++i) { v[i] *= inv_t; mx = fmaxf(mx, v[i]); }
  mx = fmaxf(mx, __shfl_xor(mx, 1));
  mx = fmaxf(mx, __shfl_xor(mx, 2));
  float sm = 0.f;
#pragma unroll
  for (int i = 0; i < 16; ++i) { v[i] = __expf(v[i] - mx); sm += v[i]; }
  sm += __shfl_xor(sm, 1);
  sm += __shfl_xor(sm, 2);
  const float r = 1.f / sm;
  ushort8 pk0, pk1;
#pragma unroll
  for (int i = 0; i < 8; ++i) { pk0[i] = f2bf(v[i] * r); pk1[i] = f2bf(v[8 + i] * r); }
  ushort8* dst = (ushort8*)(attn + (size_t)bh * 4096 + d * 64 + eb);
  dst[0] = pk0; dst[1] = pk1;
}

// ---------- K5: w2[b] = w_out @ blockdiag(attn_b)  (per (b,h): 512x64, K=64) ----------
__global__ __launch_bounds__(256) void make_w2(const unsigned short* __restrict__ attn,
                                               const float* __restrict__ w_out,
                                               unsigned short* __restrict__ w2) {
  __shared__ float sA[4096];
  const int bx = blockIdx.x;
  const int bh = bx >> 1, half = bx & 1;
  const int b = bh >> 3, h = bh & 7;
  const int t = threadIdx.x;
  for (int i = t; i < 4096; i += 256) sA[i] = bf2f(attn[(size_t)bh * 4096 + i]);
  __syncthreads();
  const int o = half * 256 + t;
  float w[64];
  const float* wp = w_out + (size_t)o * 512 + h * 64;
#pragma unroll
  for (int i = 0; i < 64; i += 4) {
    f32x4 q = *(const f32x4*)(wp + i);
    w[i] = q[0]; w[i + 1] = q[1]; w[i + 2] = q[2]; w[i + 3] = q[3];
  }
  unsigned short* dst = w2 + ((size_t)b * 512 + o) * 512 + h * 64;
#pragma unroll 1
  for (int eg = 0; eg < 8; ++eg) {
    ushort8 pk;
#pragma unroll
    for (int ee = 0; ee < 8; ++ee) {
      const int e = eg * 8 + ee;
      float acc = 0.f;
#pragma unroll
      for (int dd = 0; dd < 64; ++dd) acc += w[dd] * sA[dd * 64 + e];
      pk[ee] = f2bf(acc);
    }
    *(ushort8*)(dst + eg * 8) = pk;
  }
}

extern "C" void kernel_launch(void* const* d_in, const int* in_sizes, int n_in,
                              void* d_out, int out_size, void* d_ws, size_t ws_size,
                              hipStream_t stream) {
  const float* x     = (const float*)d_in[0];
  const float* w_qkv = (const float*)d_in[1];
  const float* w_dw  = (const float*)d_in[2];
  const float* w_out = (const float*)d_in[3];
  const float* temp  = (const float*)d_in[4];
  float* out = (float*)d_out;

  char* ws = (char*)d_ws;
  const size_t MB = 1024 * 1024;
  unsigned short* Xt    = (unsigned short*)(ws);            // 64MB  (dead after gemm1)
  float*          Spart = (float*)(ws);                     // 32MB  (reuses Xt region)
  unsigned short* attn  = (unsigned short*)(ws + 32 * MB);  // 1MB
  unsigned short* w2    = (unsigned short*)(ws + 33 * MB);  // 8MB
  unsigned short* Y     = (unsigned short*)(ws + 64 * MB);  // 192MB qkv pre-conv, channels-last
  unsigned short* Qb    = (unsigned short*)(ws + 256 * MB); // 64MB
  unsigned short* Kb    = (unsigned short*)(ws + 320 * MB); // 64MB
  unsigned short* Vb    = (unsigned short*)(ws + 384 * MB); // 64MB
  unsigned short* Wq    = (unsigned short*)(ws + 448 * MB); // 1.5MB

  cvt_f32_bf16<<<3072, 256, 0, stream>>>(w_qkv, Wq, 1536 * 512);
  transpose_x<<<dim3(64, 8, 16), 256, 0, stream>>>(x, Xt);
  // Y[(b*4096+n), o] = sum_c Xt[(b*4096+n), c] * Wq[o, c]   M=65536 N=1536 K=512
  gemm256_8ph<true><<<dim3(6, 256, 1), 512, 0, stream>>>(Xt, Wq, Y, 1536, 0, 0, 0);
  dwconv_norm<<<3072, 256, 0, stream>>>(Y, w_dw, Qb, Kb, Vb);
  attn_partial<<<512, 256, 0, stream>>>(Qb, Kb, Spart);
  softmax_attn<<<128, 256, 0, stream>>>(Spart, temp, attn);
  make_w2<<<256, 256, 0, stream>>>(attn, w_out, w2);
  // out[b, o, p] = sum_c' w2[b, o, c'] * Vb[b, p, c']   per b: M=512 N=4096 K=512
  gemm256_8ph<false><<<dim3(16, 2, 16), 512, 0, stream>>>(
      w2, Vb, out, 4096,
      (size_t)512 * 512, (size_t)4096 * 512, (size_t)512 * 4096);
}